// Round 19
// baseline (103.338 us; speedup 1.0000x reference)
//
#include <hip/hip_runtime.h>
#include <hip/hip_bf16.h>

typedef __attribute__((ext_vector_type(8))) __bf16 bf16x8;
typedef __attribute__((ext_vector_type(4))) __bf16 bf16x4;
typedef __attribute__((ext_vector_type(4))) float f32x4;

#define DIN 1024
#define DOUT 1024
#define MROWS 16384
#define POOLN 5
#define RR 8
#define NTASKS 5
#define TOPKK 3

// ---------------- shared GEMM tile body (R12 k4, verbatim, parameterized) -----
__device__ __forceinline__ void gemm_tile(const float* __restrict__ A,
                                          const __bf16* __restrict__ Bt,
                                          float* __restrict__ C,
                                          int tm, int tn, int tix,
                                          ushort* lds) {
    const int lane = tix & 63;
    const int wid  = tix >> 6;                 // 0..7
    const int wm = wid >> 2, wn = wid & 3;     // 2M x 4N wave grid

    const int ar = tix >> 2;                   // 0..127
    const int ac = tix & 3;                    // 8-float chunk
    const f32x4* __restrict__ pA = (const f32x4*)(A + ((size_t)(tm * 128 + ar)) * 1024 + ac * 8);
    const int awrp  = tix >> 3;                        // rowpair 0..63
    const int awslot= ((tix & 3) + 4 * ((tix >> 2) & 1)) ^ (awrp & 7);
    const int awoff = awrp * 64 + awslot * 8;          // ushorts within A region

    const int rpl  = lane >> 3;                // local rowpair 0..7
    const int sl   = (lane & 7) ^ rpl;         // logical c + 4*parity
    const int srow = rpl * 2 + (sl >> 2);      // 0..15
    const int sc   = sl & 3;                   // 16B k-chunk
    const char* gB = (const char*)Bt + ((size_t)(tn*256 + wid*32 + srow)) * 2048 + sc * 16;
    const int ldsBst = 4096 + wid * 1024;      // ushort idx within slab (B region)

    const int rhalf = (lane & 15) >> 1;
    const int slot  = ((lane >> 4) + 4 * (lane & 1)) ^ rhalf;
    const int aoff  = (wm * 32 + rhalf) * 64 + slot * 8;          // + p*12288 + mi*512
    const int boff  = 4096 + (wn * 32 + rhalf) * 64 + slot * 8;   // + p*12288 + ni*512

    f32x4 acc[4][4];
#pragma unroll
    for (int i = 0; i < 4; ++i)
#pragma unroll
        for (int j = 0; j < 4; ++j) acc[i][j] = (f32x4){0.f, 0.f, 0.f, 0.f};

    auto issueB = [&](int s) {
        const int p = s % 3;
        const size_t kb = (size_t)s * 64;      // 32 bf16 = 64 B per k-slab
#pragma unroll
        for (int j = 0; j < 2; ++j) {
            __builtin_amdgcn_global_load_lds(
                (const __attribute__((address_space(1))) void*)(gB + (size_t)j * 32768 + kb),
                (__attribute__((address_space(3))) void*)&lds[p * 12288 + ldsBst + j * 512],
                16, 0, 0);
        }
    };

    auto writeA = [&](int s, f32x4 a0, f32x4 a1) {
        const int p = s % 3;
        bf16x8 v = { (__bf16)a0[0], (__bf16)a0[1], (__bf16)a0[2], (__bf16)a0[3],
                     (__bf16)a1[0], (__bf16)a1[1], (__bf16)a1[2], (__bf16)a1[3] };
        *(bf16x8*)&lds[p * 12288 + awoff] = v;
    };

    auto computeSlab = [&](int s) {
        const int p = s % 3;
        const ushort* aB = &lds[p * 12288 + aoff];
        const ushort* bB = &lds[p * 12288 + boff];
        bf16x8 a[4], b[4];
#pragma unroll
        for (int mi = 0; mi < 4; ++mi) a[mi] = *(const bf16x8*)(aB + mi * 512);
#pragma unroll
        for (int ni = 0; ni < 4; ++ni) b[ni] = *(const bf16x8*)(bB + ni * 512);
        __builtin_amdgcn_s_setprio(1);
#pragma unroll
        for (int mi = 0; mi < 4; ++mi)
#pragma unroll
            for (int ni = 0; ni < 4; ++ni)
                acc[mi][ni] = __builtin_amdgcn_mfma_f32_16x16x32_bf16(
                    a[mi], b[ni], acc[mi][ni], 0, 0, 0);
        __builtin_amdgcn_s_setprio(0);
    };

    f32x4 pa0 = pA[0], pa1 = pA[1];            // A(0)
    issueB(0);
    f32x4 na0 = pA[8], na1 = pA[9];            // A(1)
    issueB(1);
    asm volatile("s_waitcnt vmcnt(6)" ::: "memory");   // retire A(0) regs
    writeA(0, pa0, pa1);
    asm volatile("s_waitcnt lgkmcnt(0)" ::: "memory"); // A(0) visible pre-loop

#pragma unroll 1
    for (int s = 0; s < 32; ++s) {
        if (s < 31) {
            asm volatile("s_waitcnt vmcnt(2)" ::: "memory");  // retire B(s)+Areg(s+1)
            writeA(s + 1, na0, na1);
        } else {
            asm volatile("s_waitcnt vmcnt(0)" ::: "memory");
        }
        if (s < 30) {
            na0 = pA[(size_t)(s + 2) * 8];
            na1 = pA[(size_t)(s + 2) * 8 + 1];
            issueB(s + 2);
        }
        __builtin_amdgcn_s_barrier();                         // slab s fully staged
        asm volatile("" ::: "memory");
        computeSlab(s);
        asm volatile("" ::: "memory");
        asm volatile("s_waitcnt lgkmcnt(0)" ::: "memory");    // drain writeA(s+1), overlapped
        __builtin_amdgcn_s_barrier();
    }

#pragma unroll
    for (int mi = 0; mi < 4; ++mi) {
#pragma unroll
        for (int r = 0; r < 4; ++r) {
            const int grow = tm * 128 + wm * 64 + mi * 16 + (lane >> 4) * 4 + r;
            float* cp = C + (size_t)grow * 1024 + tn * 256 + wn * 64 + (lane & 15);
#pragma unroll
            for (int ni = 0; ni < 4; ++ni) cp[ni * 16] = acc[mi][ni][r];
        }
    }
}

// ---------------- kW: W f32 -> Wb0 bf16 (no dependencies) ---------------------
__global__ __launch_bounds__(256) void kW_cvt(const float* __restrict__ W,
                                              __bf16* __restrict__ Wb0) {
    const size_t i = (size_t)(blockIdx.x * 256 + threadIdx.x) * 8;
    f32x4 a = *(const f32x4*)&W[i];
    f32x4 b = *(const f32x4*)&W[i + 4];
    bf16x8 v = { (__bf16)a[0], (__bf16)a[1], (__bf16)a[2], (__bf16)a[3],
                 (__bf16)b[0], (__bf16)b[1], (__bf16)b[2], (__bf16)b[3] };
    *(bf16x8*)&Wb0[i] = v;
}

// ---------------- k1: lower GEMM ∥ colsum, flavor-interleaved per CU ----------
// 512 blocks x 512 thr = 2 blocks/CU. Dispatch: XCD = bid&7; within an XCD the
// sequence j = bid>>3 fills CUs in consecutive PAIRS. R18 paired (GEMM,GEMM) on
// half the CUs (flavor was bid<256) -> two tiles serialized per CU. Fix: flavor
// = j&1 so every CU gets exactly one GEMM + one colsum block; index = within-
// XCD position q = bid>>4 (x32 per XCD).
__global__ __launch_bounds__(512, 4) void k1_mix(const float* __restrict__ in,
                                                 const __bf16* __restrict__ Wb0,
                                                 float* __restrict__ C,
                                                 float* __restrict__ partial) {
    __shared__ ushort lds[36864];              // 72 KB (GEMM path only)
    const int bid = blockIdx.x;
    const int x   = bid & 7;                   // XCD
    const int q   = bid >> 4;                  // within-XCD pair index 0..31
    if (((bid >> 3) & 1) == 0) {
        // ---- GEMM flavor: g = x*32+q in 0..255 -> tm 0..63, tn 0..3 (XCD-local A)
        gemm_tile(in, Wb0, C, x * 8 + (q >> 2), q & 3, threadIdx.x, lds);
        return;
    }
    // ---- colsum flavor: cb = x*32+q in 0..255; rows cb*64 .. cb*64+63
    const int cb = x * 32 + q;
    const int t  = threadIdx.x;
    const int cq = t & 255;                    // f32x4 column index
    const int h  = t >> 8;                     // row half 0/1 (32 rows each)
    const f32x4* __restrict__ base = (const f32x4*)in
        + ((size_t)(cb * 64 + h * 32)) * 256 + cq;
    float s0 = 0.f, s1 = 0.f, s2 = 0.f, s3 = 0.f;
#pragma unroll 1
    for (int j = 0; j < 4; ++j) {              // 4 batches x 8 rows = 32 rows
        const f32x4* p = base + (size_t)j * 8 * 256;
        f32x4 v0 = p[0];
        f32x4 v1 = p[256];
        f32x4 v2 = p[512];
        f32x4 v3 = p[768];
        f32x4 v4 = p[1024];
        f32x4 v5 = p[1280];
        f32x4 v6 = p[1536];
        f32x4 v7 = p[1792];
        s0 += v0[0] + v1[0] + v2[0] + v3[0] + v4[0] + v5[0] + v6[0] + v7[0];
        s1 += v0[1] + v1[1] + v2[1] + v3[1] + v4[1] + v5[1] + v6[1] + v7[1];
        s2 += v0[2] + v1[2] + v2[2] + v3[2] + v4[2] + v5[2] + v6[2] + v7[2];
        s3 += v0[3] + v1[3] + v2[3] + v3[3] + v4[3] + v5[3] + v6[3] + v7[3];
    }
    f32x4 pv = { s0, s1, s2, s3 };
    *(f32x4*)&partial[(size_t)(cb * 2 + h) * DIN + cq * 4] = pv;
}

// ---------------- k1b: reduce partial[512][1024] -> partial2[8][1024] ---------
__global__ __launch_bounds__(256) void k1b_reduce(const float* __restrict__ partial,
                                                  float* __restrict__ partial2) {
    const int tid = blockIdx.x * 256 + threadIdx.x;      // 0..8191
    const int c = tid & (DIN - 1);
    const int g = tid >> 10;                             // 0..7
    float s = 0.f;
    const int r0 = g * 64;
#pragma unroll 8
    for (int r = r0; r < r0 + 64; ++r)
        s += partial[(size_t)r * DIN + c];
    partial2[(size_t)g * DIN + c] = s;
}

// ---------------- k23b: gate (redundant per block) + Wb1 build ----------------
__global__ __launch_bounds__(256) void k23b_weights(const float* __restrict__ partial2,
                                                    const float* __restrict__ lroute,
                                                    const int* __restrict__ task_id_p,
                                                    const float* __restrict__ W,
                                                    const float* __restrict__ ldown,
                                                    const float* __restrict__ lup,
                                                    __bf16* __restrict__ Wb1) {
    __shared__ float red[4][POOLN];
    __shared__ float sgate[TOPKK];
    __shared__ int   sgidx[TOPKK];
    const int tix = threadIdx.x;
    const int w = tix >> 6, l = tix & 63;

    float part[POOLN] = {0.f, 0.f, 0.f, 0.f, 0.f};
    {
        const int d0 = tix * 4;
#pragma unroll
        for (int dd = 0; dd < 4; ++dd) {
            const int d = d0 + dd;
            float cs = 0.f;
#pragma unroll
            for (int g = 0; g < 8; ++g) cs += partial2[g * DIN + d];
            cs *= (1.0f / (float)MROWS);
            const float* rp = &lroute[(size_t)1 * DIN * POOLN + (size_t)d * POOLN];
#pragma unroll
            for (int p = 0; p < POOLN; ++p) part[p] += cs * rp[p];
        }
    }
#pragma unroll
    for (int p = 0; p < POOLN; ++p) {
        float v = part[p];
        for (int off = 32; off; off >>= 1) v += __shfl_down(v, off);
        if (l == 0) red[w][p] = v;
    }
    __syncthreads();
    if (tix == 0) {
#pragma unroll
        for (int p = 0; p < POOLN; ++p)
            part[p] = red[0][p] + red[1][p] + red[2][p] + red[3][p];
        int tid = *task_id_p;
        if (tid > NTASKS) tid = NTASKS;
        int L = tid < (POOLN - 1) ? tid : (POOLN - 1);   // slice [1:tid+1] clamps
        int k = tid < TOPKK ? tid : TOPKK;
        float sl[POOLN];
        for (int j = 0; j < L; ++j) sl[j] = part[1 + j];
        float G[TOPKK]; int I[TOPKK];
        int used = 0;
        for (int j = 0; j < k; ++j) {
            int best = -1; float bv = 0.f;
            for (int i2 = 0; i2 < L; ++i2) {
                if (used & (1 << i2)) continue;
                if (best < 0 || sl[i2] > bv) { bv = sl[i2]; best = i2; }
            }
            used |= 1 << best; G[j] = bv; I[j] = best;
        }
        float gt[TOPKK] = {0.f, 0.f, 0.f};
        int   gi[TOPKK] = {0, 0, 0};
        if (k > 0) {
            float m = G[0];           // descending -> max first
            float e[TOPKK]; float se = 0.f;
            for (int j = 0; j < k; ++j) { e[j] = expf(G[j] - m); se += e[j]; }
            for (int j = 0; j < k; ++j) { gt[j] = e[j] / se; gi[j] = I[j]; }
        }
#pragma unroll
        for (int j = 0; j < TOPKK; ++j) { sgate[j] = gt[j]; sgidx[j] = gi[j]; }
    }
    __syncthreads();

    const int o = blockIdx.x;
    float c[TOPKK][RR];
#pragma unroll
    for (int j = 0; j < TOPKK; ++j) {
        const float g = sgate[j];
        const int   p = sgidx[j];
#pragma unroll
        for (int r = 0; r < RR; ++r)
            c[j][r] = g * lup[(size_t)p * RR * DOUT + (size_t)r * DOUT + o];
    }
    const int d0 = tix * 4;
    const float4 wv = *(const float4*)&W[(size_t)o * DIN + d0];
    float dwv[4] = { 0.f, 0.f, 0.f, 0.f };
#pragma unroll
    for (int j = 0; j < TOPKK; ++j) {
        const int p = sgidx[j];
#pragma unroll
        for (int dd = 0; dd < 4; ++dd) {
            const float4 da = *(const float4*)&ldown[(size_t)p * DIN * RR + (size_t)(d0 + dd) * RR];
            const float4 db = *(const float4*)&ldown[(size_t)p * DIN * RR + (size_t)(d0 + dd) * RR + 4];
            dwv[dd] += da.x * c[j][0] + da.y * c[j][1] + da.z * c[j][2] + da.w * c[j][3]
                     + db.x * c[j][4] + db.y * c[j][5] + db.z * c[j][6] + db.w * c[j][7];
        }
    }
    bf16x4 b1 = { (__bf16)(wv.x + dwv[0]), (__bf16)(wv.y + dwv[1]),
                  (__bf16)(wv.z + dwv[2]), (__bf16)(wv.w + dwv[3]) };
    *(bf16x4*)&Wb1[(size_t)o * DIN + d0] = b1;
}

// ---------------- k3: upper-half GEMM (rows>=8192, B=Wb1) ---------------------
__global__ __launch_bounds__(512, 4) void k3_gemm(const float* __restrict__ in,
                                                  const __bf16* __restrict__ Wb1,
                                                  float* __restrict__ C) {
    __shared__ ushort lds[36864];
    const int bid = blockIdx.x;                // 0..255
    const int xcd = bid & 7;
    const int idx = bid >> 3;                  // 0..31
    gemm_tile(in, Wb1, C, 64 + xcd * 8 + (idx >> 2), idx & 3, threadIdx.x, lds);
}

extern "C" void kernel_launch(void* const* d_in, const int* in_sizes, int n_in,
                              void* d_out, int out_size, void* d_ws, size_t ws_size,
                              hipStream_t stream) {
    const float* in     = (const float*)d_in[0];
    const float* W      = (const float*)d_in[1];
    const float* ldown  = (const float*)d_in[2];
    const float* lup    = (const float*)d_in[3];
    const float* lroute = (const float*)d_in[4];
    const int*   taskid = (const int*)d_in[5];
    float* out = (float*)d_out;

    // workspace carve (~6.1 MB)
    __bf16* Wb0      = (__bf16*)d_ws;                           // 2 MB
    __bf16* Wb1      = Wb0 + (size_t)DOUT * DIN;                // 2 MB
    float*  partial  = (float*)(Wb1 + (size_t)DOUT * DIN);      // 2 MB
    float*  partial2 = partial + 512 * DIN;                     // 32 KB

    kW_cvt<<<512, 256, 0, stream>>>(W, Wb0);
    k1_mix<<<512, 512, 0, stream>>>(in, Wb0, out, partial);
    k1b_reduce<<<32, 256, 0, stream>>>(partial, partial2);
    k23b_weights<<<1024, 256, 0, stream>>>(partial2, lroute, taskid, W, ldown, lup, Wb1);
    k3_gemm<<<256, 512, 0, stream>>>(in, Wb1, out);
}

// Round 20
// 89.486 us; speedup vs baseline: 1.1548x; 1.1548x over previous
//
#include <hip/hip_runtime.h>
#include <hip/hip_bf16.h>

typedef __attribute__((ext_vector_type(8))) __bf16 bf16x8;
typedef __attribute__((ext_vector_type(4))) __bf16 bf16x4;
typedef __attribute__((ext_vector_type(4))) float f32x4;

#define DIN 1024
#define DOUT 1024
#define MROWS 16384
#define POOLN 5
#define RR 8
#define NTASKS 5
#define TOPKK 3

// ------------- gemm_tile128: 128x128 tile, 8 waves, BK=32, 48KB LDS ----------
// Derived from the validated 128x256 body: A path byte-identical; B path is the
// same 16-row-group staging with ONE group per wave (8x16=128 rows); readers
// use the same rowpair/slot swizzle. vmcnt re-derived: prologue A0(2)B0(1)A1(2)
// B1(1)=6 outstanding -> vmcnt(4) retires A0; steady state 4 outstanding ->
// vmcnt(1) retires B(s)+A(s+1), leaves B(s+1).
__device__ __forceinline__ void gemm_tile128(const float* __restrict__ A,
                                             const __bf16* __restrict__ Bt,
                                             float* __restrict__ C,
                                             int tm, int tn, int tix,
                                             ushort* lds) {
    const int lane = tix & 63;
    const int wid  = tix >> 6;                 // 0..7
    const int wm = wid >> 2, wn = wid & 3;     // 2M x 4N; wave tile 64x32

    // ---- A staging (reg->cvt->ds_write), identical to validated body
    const int ar = tix >> 2;                   // 0..127
    const int ac = tix & 3;                    // 8-float chunk
    const f32x4* __restrict__ pA = (const f32x4*)(A + ((size_t)(tm * 128 + ar)) * 1024 + ac * 8);
    const int awrp  = tix >> 3;                        // rowpair 0..63
    const int awslot= ((tix & 3) + 4 * ((tix >> 2) & 1)) ^ (awrp & 7);
    const int awoff = awrp * 64 + awslot * 8;          // ushorts within A region

    // ---- B staging: wave wid stages rows wid*16..wid*16+15 (one group)
    const int rpl  = lane >> 3;                // local rowpair 0..7
    const int sl   = (lane & 7) ^ rpl;         // logical c + 4*parity
    const int srow = rpl * 2 + (sl >> 2);      // 0..15
    const int sc   = sl & 3;                   // 16B k-chunk
    const char* gB = (const char*)Bt + ((size_t)(tn*128 + wid*16 + srow)) * 2048 + sc * 16;
    const int ldsBst = 4096 + wid * 512;       // B region 4096..8191

    // ---- readers (same rowpair/slot algebra)
    const int rhalf = (lane & 15) >> 1;
    const int slot  = ((lane >> 4) + 4 * (lane & 1)) ^ rhalf;
    const int aoff  = (wm * 32 + rhalf) * 64 + slot * 8;          // + p*8192 + mi*512
    const int boff  = 4096 + (wn * 16 + rhalf) * 64 + slot * 8;   // + p*8192 + ni*512

    f32x4 acc[4][2];
#pragma unroll
    for (int i = 0; i < 4; ++i)
#pragma unroll
        for (int j = 0; j < 2; ++j) acc[i][j] = (f32x4){0.f, 0.f, 0.f, 0.f};

    auto issueB = [&](int s) {
        const int p = s % 3;
        const size_t kb = (size_t)s * 64;      // 32 bf16 = 64 B per k-slab
        __builtin_amdgcn_global_load_lds(
            (const __attribute__((address_space(1))) void*)(gB + kb),
            (__attribute__((address_space(3))) void*)&lds[p * 8192 + ldsBst],
            16, 0, 0);
    };

    auto writeA = [&](int s, f32x4 a0, f32x4 a1) {
        const int p = s % 3;
        bf16x8 v = { (__bf16)a0[0], (__bf16)a0[1], (__bf16)a0[2], (__bf16)a0[3],
                     (__bf16)a1[0], (__bf16)a1[1], (__bf16)a1[2], (__bf16)a1[3] };
        *(bf16x8*)&lds[p * 8192 + awoff] = v;
    };

    auto computeSlab = [&](int s) {
        const int p = s % 3;
        const ushort* aB = &lds[p * 8192 + aoff];
        const ushort* bB = &lds[p * 8192 + boff];
        bf16x8 a[4], b[2];
#pragma unroll
        for (int mi = 0; mi < 4; ++mi) a[mi] = *(const bf16x8*)(aB + mi * 512);
#pragma unroll
        for (int ni = 0; ni < 2; ++ni) b[ni] = *(const bf16x8*)(bB + ni * 512);
        __builtin_amdgcn_s_setprio(1);
#pragma unroll
        for (int mi = 0; mi < 4; ++mi)
#pragma unroll
            for (int ni = 0; ni < 2; ++ni)
                acc[mi][ni] = __builtin_amdgcn_mfma_f32_16x16x32_bf16(
                    a[mi], b[ni], acc[mi][ni], 0, 0, 0);
        __builtin_amdgcn_s_setprio(0);
    };

    f32x4 pa0 = pA[0], pa1 = pA[1];            // A(0)
    issueB(0);
    f32x4 na0 = pA[8], na1 = pA[9];            // A(1)
    issueB(1);
    asm volatile("s_waitcnt vmcnt(4)" ::: "memory");   // retire A(0) regs
    writeA(0, pa0, pa1);
    asm volatile("s_waitcnt lgkmcnt(0)" ::: "memory"); // A(0) visible pre-loop

#pragma unroll 1
    for (int s = 0; s < 32; ++s) {
        if (s < 31) {
            asm volatile("s_waitcnt vmcnt(1)" ::: "memory");  // retire B(s)+Areg(s+1)
            writeA(s + 1, na0, na1);
        } else {
            asm volatile("s_waitcnt vmcnt(0)" ::: "memory");
        }
        if (s < 30) {
            na0 = pA[(size_t)(s + 2) * 8];
            na1 = pA[(size_t)(s + 2) * 8 + 1];
            issueB(s + 2);
        }
        __builtin_amdgcn_s_barrier();                         // slab s fully staged
        asm volatile("" ::: "memory");
        computeSlab(s);
        asm volatile("" ::: "memory");
        asm volatile("s_waitcnt lgkmcnt(0)" ::: "memory");    // drain writeA(s+1), overlapped
        __builtin_amdgcn_s_barrier();
    }

#pragma unroll
    for (int mi = 0; mi < 4; ++mi) {
#pragma unroll
        for (int r = 0; r < 4; ++r) {
            const int grow = tm * 128 + wm * 64 + mi * 16 + (lane >> 4) * 4 + r;
            float* cp = C + (size_t)grow * 1024 + tn * 128 + wn * 32 + (lane & 15);
#pragma unroll
            for (int ni = 0; ni < 2; ++ni) cp[ni * 16] = acc[mi][ni][r];
        }
    }
}

// ---------------- kW: W f32 -> Wb0 bf16 (no dependencies) ---------------------
__global__ __launch_bounds__(256) void kW_cvt(const float* __restrict__ W,
                                              __bf16* __restrict__ Wb0) {
    const size_t i = (size_t)(blockIdx.x * 256 + threadIdx.x) * 8;
    f32x4 a = *(const f32x4*)&W[i];
    f32x4 b = *(const f32x4*)&W[i + 4];
    bf16x8 v = { (__bf16)a[0], (__bf16)a[1], (__bf16)a[2], (__bf16)a[3],
                 (__bf16)b[0], (__bf16)b[1], (__bf16)b[2], (__bf16)b[3] };
    *(bf16x8*)&Wb0[i] = v;
}

// ---------------- k1: lower GEMM (512 x 128² tiles) ∥ colsum (256 blk) --------
// 768 blocks x 512 thr, 48KB LDS -> 3 blocks/CU, ALL co-resident at launch.
// Dispatch passes (one block per CU per pass): pass1+2 = GEMM (bids 0..511),
// pass3 = colsum (bids 512..767) -> every CU gets 2 GEMM + 1 colsum.
__global__ __launch_bounds__(512, 6) void k1_mix(const float* __restrict__ in,
                                                 const __bf16* __restrict__ Wb0,
                                                 float* __restrict__ C,
                                                 float* __restrict__ partial) {
    __shared__ ushort lds[24576];              // 48 KB
    const int bid = blockIdx.x;
    if (bid < 512) {
        const int xcd = bid & 7;
        const int j   = bid >> 3;              // 0..63 per-XCD sequence
        gemm_tile128(in, Wb0, C, xcd * 8 + (j >> 3), j & 7, threadIdx.x, lds);
        return;
    }
    // ---- colsum: block cb covers rows cb*64 .. cb*64+63 (R18-validated path)
    const int cb = bid - 512;                  // 0..255
    const int t  = threadIdx.x;
    const int cq = t & 255;                    // f32x4 column index
    const int h  = t >> 8;                     // row half 0/1 (32 rows each)
    const f32x4* __restrict__ base = (const f32x4*)in
        + ((size_t)(cb * 64 + h * 32)) * 256 + cq;
    float s0 = 0.f, s1 = 0.f, s2 = 0.f, s3 = 0.f;
#pragma unroll 1
    for (int j = 0; j < 4; ++j) {              // 4 batches x 8 rows = 32 rows
        const f32x4* p = base + (size_t)j * 8 * 256;
        f32x4 v0 = p[0];
        f32x4 v1 = p[256];
        f32x4 v2 = p[512];
        f32x4 v3 = p[768];
        f32x4 v4 = p[1024];
        f32x4 v5 = p[1280];
        f32x4 v6 = p[1536];
        f32x4 v7 = p[1792];
        s0 += v0[0] + v1[0] + v2[0] + v3[0] + v4[0] + v5[0] + v6[0] + v7[0];
        s1 += v0[1] + v1[1] + v2[1] + v3[1] + v4[1] + v5[1] + v6[1] + v7[1];
        s2 += v0[2] + v1[2] + v2[2] + v3[2] + v4[2] + v5[2] + v6[2] + v7[2];
        s3 += v0[3] + v1[3] + v2[3] + v3[3] + v4[3] + v5[3] + v6[3] + v7[3];
    }
    f32x4 pv = { s0, s1, s2, s3 };
    *(f32x4*)&partial[(size_t)(cb * 2 + h) * DIN + cq * 4] = pv;
}

// ---------------- k1b: reduce partial[512][1024] -> partial2[8][1024] ---------
__global__ __launch_bounds__(256) void k1b_reduce(const float* __restrict__ partial,
                                                  float* __restrict__ partial2) {
    const int tid = blockIdx.x * 256 + threadIdx.x;      // 0..8191
    const int c = tid & (DIN - 1);
    const int g = tid >> 10;                             // 0..7
    float s = 0.f;
    const int r0 = g * 64;
#pragma unroll 8
    for (int r = r0; r < r0 + 64; ++r)
        s += partial[(size_t)r * DIN + c];
    partial2[(size_t)g * DIN + c] = s;
}

// ---------------- k23b: gate (redundant per block) + Wb1 build ----------------
__global__ __launch_bounds__(256) void k23b_weights(const float* __restrict__ partial2,
                                                    const float* __restrict__ lroute,
                                                    const int* __restrict__ task_id_p,
                                                    const float* __restrict__ W,
                                                    const float* __restrict__ ldown,
                                                    const float* __restrict__ lup,
                                                    __bf16* __restrict__ Wb1) {
    __shared__ float red[4][POOLN];
    __shared__ float sgate[TOPKK];
    __shared__ int   sgidx[TOPKK];
    const int tix = threadIdx.x;
    const int w = tix >> 6, l = tix & 63;

    float part[POOLN] = {0.f, 0.f, 0.f, 0.f, 0.f};
    {
        const int d0 = tix * 4;
#pragma unroll
        for (int dd = 0; dd < 4; ++dd) {
            const int d = d0 + dd;
            float cs = 0.f;
#pragma unroll
            for (int g = 0; g < 8; ++g) cs += partial2[g * DIN + d];
            cs *= (1.0f / (float)MROWS);
            const float* rp = &lroute[(size_t)1 * DIN * POOLN + (size_t)d * POOLN];
#pragma unroll
            for (int p = 0; p < POOLN; ++p) part[p] += cs * rp[p];
        }
    }
#pragma unroll
    for (int p = 0; p < POOLN; ++p) {
        float v = part[p];
        for (int off = 32; off; off >>= 1) v += __shfl_down(v, off);
        if (l == 0) red[w][p] = v;
    }
    __syncthreads();
    if (tix == 0) {
#pragma unroll
        for (int p = 0; p < POOLN; ++p)
            part[p] = red[0][p] + red[1][p] + red[2][p] + red[3][p];
        int tid = *task_id_p;
        if (tid > NTASKS) tid = NTASKS;
        int L = tid < (POOLN - 1) ? tid : (POOLN - 1);   // slice [1:tid+1] clamps
        int k = tid < TOPKK ? tid : TOPKK;
        float sl[POOLN];
        for (int j = 0; j < L; ++j) sl[j] = part[1 + j];
        float G[TOPKK]; int I[TOPKK];
        int used = 0;
        for (int j = 0; j < k; ++j) {
            int best = -1; float bv = 0.f;
            for (int i2 = 0; i2 < L; ++i2) {
                if (used & (1 << i2)) continue;
                if (best < 0 || sl[i2] > bv) { bv = sl[i2]; best = i2; }
            }
            used |= 1 << best; G[j] = bv; I[j] = best;
        }
        float gt[TOPKK] = {0.f, 0.f, 0.f};
        int   gi[TOPKK] = {0, 0, 0};
        if (k > 0) {
            float m = G[0];           // descending -> max first
            float e[TOPKK]; float se = 0.f;
            for (int j = 0; j < k; ++j) { e[j] = expf(G[j] - m); se += e[j]; }
            for (int j = 0; j < k; ++j) { gt[j] = e[j] / se; gi[j] = I[j]; }
        }
#pragma unroll
        for (int j = 0; j < TOPKK; ++j) { sgate[j] = gt[j]; sgidx[j] = gi[j]; }
    }
    __syncthreads();

    const int o = blockIdx.x;
    float c[TOPKK][RR];
#pragma unroll
    for (int j = 0; j < TOPKK; ++j) {
        const float g = sgate[j];
        const int   p = sgidx[j];
#pragma unroll
        for (int r = 0; r < RR; ++r)
            c[j][r] = g * lup[(size_t)p * RR * DOUT + (size_t)r * DOUT + o];
    }
    const int d0 = tix * 4;
    const float4 wv = *(const float4*)&W[(size_t)o * DIN + d0];
    float dwv[4] = { 0.f, 0.f, 0.f, 0.f };
#pragma unroll
    for (int j = 0; j < TOPKK; ++j) {
        const int p = sgidx[j];
#pragma unroll
        for (int dd = 0; dd < 4; ++dd) {
            const float4 da = *(const float4*)&ldown[(size_t)p * DIN * RR + (size_t)(d0 + dd) * RR];
            const float4 db = *(const float4*)&ldown[(size_t)p * DIN * RR + (size_t)(d0 + dd) * RR + 4];
            dwv[dd] += da.x * c[j][0] + da.y * c[j][1] + da.z * c[j][2] + da.w * c[j][3]
                     + db.x * c[j][4] + db.y * c[j][5] + db.z * c[j][6] + db.w * c[j][7];
        }
    }
    bf16x4 b1 = { (__bf16)(wv.x + dwv[0]), (__bf16)(wv.y + dwv[1]),
                  (__bf16)(wv.z + dwv[2]), (__bf16)(wv.w + dwv[3]) };
    *(bf16x4*)&Wb1[(size_t)o * DIN + d0] = b1;
}

// ---------------- k3: upper-half GEMM (rows>=8192, B=Wb1), 512 x 128² ---------
__global__ __launch_bounds__(512, 6) void k3_gemm(const float* __restrict__ in,
                                                  const __bf16* __restrict__ Wb1,
                                                  float* __restrict__ C) {
    __shared__ ushort lds[24576];
    const int bid = blockIdx.x;                // 0..511
    const int xcd = bid & 7;
    const int j   = bid >> 3;                  // 0..63
    gemm_tile128(in, Wb1, C, 64 + xcd * 8 + (j >> 3), j & 7, threadIdx.x, lds);
}

extern "C" void kernel_launch(void* const* d_in, const int* in_sizes, int n_in,
                              void* d_out, int out_size, void* d_ws, size_t ws_size,
                              hipStream_t stream) {
    const float* in     = (const float*)d_in[0];
    const float* W      = (const float*)d_in[1];
    const float* ldown  = (const float*)d_in[2];
    const float* lup    = (const float*)d_in[3];
    const float* lroute = (const float*)d_in[4];
    const int*   taskid = (const int*)d_in[5];
    float* out = (float*)d_out;

    // workspace carve (~6.1 MB)
    __bf16* Wb0      = (__bf16*)d_ws;                           // 2 MB
    __bf16* Wb1      = Wb0 + (size_t)DOUT * DIN;                // 2 MB
    float*  partial  = (float*)(Wb1 + (size_t)DOUT * DIN);      // 2 MB
    float*  partial2 = partial + 512 * DIN;                     // 32 KB

    kW_cvt<<<512, 256, 0, stream>>>(W, Wb0);
    k1_mix<<<768, 512, 0, stream>>>(in, Wb0, out, partial);
    k1b_reduce<<<32, 256, 0, stream>>>(partial, partial2);
    k23b_weights<<<1024, 256, 0, stream>>>(partial2, lroute, taskid, W, ldown, lup, Wb1);
    k3_gemm<<<512, 512, 0, stream>>>(in, Wb1, out);
}